// Round 13
// baseline (756.589 us; speedup 1.0000x reference)
//
#include <hip/hip_runtime.h>
#include <cstdint>
#include <cmath>

// Problem constants
static constexpr int V_  = 50000;
static constexpr int E_  = 300;
static constexpr int C_  = 128;
static constexpr int B_  = 128;
static constexpr int SC_ = 512;
static constexpr int SE_ = 64;
static constexpr int NCOL = 768;   // [fw_gate 256 | fw_cand 128 | bw_gate 256 | bw_cand 128]
static constexpr int KP  = 320;    // K padded to 10 x 32 for MFMA

// ws layout (float offsets)
static constexpr size_t OFF_PROJ  = 0;
static constexpr size_t SZ_PROJ   = (size_t)V_ * NCOL;
static constexpr size_t OFF_WXP   = OFF_PROJ + SZ_PROJ;   // (unused now, kept for layout stability)
static constexpr size_t SZ_WXP    = (size_t)304 * NCOL;
static constexpr size_t OFF_UALL  = OFF_WXP + SZ_WXP;
static constexpr size_t SZ_UALL   = (size_t)C_ * NCOL;
static constexpr size_t OFF_BIAS  = OFF_UALL + SZ_UALL;
static constexpr size_t SZ_BIAS   = NCOL;
static constexpr size_t OFF_ST    = OFF_BIAS + SZ_BIAS;
static constexpr size_t SZ_ST_CTX = (size_t)B_ * SC_ * C_;
static constexpr size_t SZ_ST_END = (size_t)B_ * SE_ * C_;
static constexpr size_t SZ_ST     = 2*SZ_ST_CTX + 2*SZ_ST_END;    // 75.5 MB
static constexpr size_t OFF_FEATS = OFF_ST + SZ_ST;
static constexpr size_t SZ_FEATS  = (size_t)B_ * 512;
static constexpr size_t OFF_BT    = OFF_FEATS + SZ_FEATS;
static constexpr size_t SZ_BT     = (size_t)NCOL * KP / 2 * 2;    // 2 short arrays (245760 floats)
static constexpr size_t OFF_AWT   = OFF_BT + SZ_BT;               // att_w^T hi/lo shorts
// Partials buffer for split attention REUSES the Bt region (dead after gemm):
// 512 chains x 2 halves x (m, l, acc[128]) = 133120 floats < 245760.
// A_hi/A_lo (bf16) OVERLAP the states region (dead once gemm ends; recur
// zeroes its own tail rows so no global memset is needed).

typedef __attribute__((ext_vector_type(8))) short bf16x8;
typedef __attribute__((ext_vector_type(4))) float f32x4;

static __device__ __forceinline__ unsigned short f2bf_rne(float f) {
  unsigned u = __float_as_uint(f);
  unsigned r = u + 0x7fffu + ((u >> 16) & 1u);
  return (unsigned short)(r >> 16);
}

static __device__ __forceinline__ void gload_lds16(const short* g, short* l) {
  __builtin_amdgcn_global_load_lds(
      (const __attribute__((address_space(1))) void*)g,
      (__attribute__((address_space(3))) void*)l, 16, 0, 0);
}

// fast activations: __expf + v_rcp_f32 (~1e-6 rel err; logit threshold 7.4e-5)
static __device__ __forceinline__ float fast_sigmoid(float x) {
  return __builtin_amdgcn_rcpf(1.f + __expf(-x));
}
static __device__ __forceinline__ float fast_tanh(float x) {
  return fmaf(-2.f, __builtin_amdgcn_rcpf(__expf(2.f * x) + 1.f), 1.f);
}

// ---------------------------------------------------------------------------
// pack_misc: Bt hi/lo DIRECT from raw weights (Wxp buffer deleted), att_w^T
// hi/lo, Uall[128][768], bias[768] — one dispatch, no inter-pack dependency.
// ---------------------------------------------------------------------------
__global__ void pack_misc(const float* __restrict__ fw_gw, const float* __restrict__ fw_gb,
                          const float* __restrict__ fw_cw, const float* __restrict__ fw_cb,
                          const float* __restrict__ bw_gw, const float* __restrict__ bw_gb,
                          const float* __restrict__ bw_cw, const float* __restrict__ bw_cb,
                          const float* __restrict__ att_w,
                          float* __restrict__ Uall, float* __restrict__ bias,
                          short* __restrict__ Bthi, short* __restrict__ Btlo,
                          short* __restrict__ awt_hi, short* __restrict__ awt_lo) {
  int i = blockIdx.x * 256 + threadIdx.x;
  if (i < NCOL * KP) {
    int k = i % KP, n = i / KP;
    float v = 0.f;
    if (k < 300) {
      if (n < 256)      v = fw_gw[k*256 + n];
      else if (n < 384) v = fw_cw[k*128 + (n-256)];
      else if (n < 640) v = bw_gw[k*256 + (n-384)];
      else              v = bw_cw[k*128 + (n-640)];
    }
    unsigned short h = f2bf_rne(v);
    float hf = __uint_as_float((unsigned)h << 16);
    Bthi[i] = (short)h;
    Btlo[i] = (short)f2bf_rne(v - hf);
    return;
  }
  int j = i - NCOL * KP;
  if (j < 128 * 128) {
    int d = j >> 7, c = j & 127;
    float v = att_w[(size_t)c * 128 + d];   // transpose: awt[d][k=c]
    unsigned short h = f2bf_rne(v);
    float hf = __uint_as_float((unsigned)h << 16);
    awt_hi[j] = (short)h;
    awt_lo[j] = (short)f2bf_rne(v - hf);
    return;
  }
  j -= 128 * 128;
  if (j < 128 * NCOL) {
    int k = j / NCOL, c = j % NCOL;
    int kk = 300 + k;
    float v;
    if (c < 256)      v = fw_gw[kk*256 + c];
    else if (c < 384) v = fw_cw[kk*128 + (c-256)];
    else if (c < 640) v = bw_gw[kk*256 + (c-384)];
    else              v = bw_cw[kk*128 + (c-640)];
    Uall[j] = v;
    return;
  }
  j -= 128 * NCOL;
  if (j < NCOL) {
    float v;
    if (j < 256)      v = fw_gb[j];
    else if (j < 384) v = fw_cb[j-256];
    else if (j < 640) v = bw_gb[j-384];
    else              v = bw_cb[j-640];
    bias[j] = v;
  }
}

__global__ void pack_emb(const float* __restrict__ emb, short* __restrict__ Ahi,
                         short* __restrict__ Alo) {
  size_t i = (size_t)blockIdx.x * 256 + threadIdx.x;
  if (i >= (size_t)V_ * KP) return;
  int k = (int)(i % KP);
  size_t row = i / KP;
  float v = (k < E_) ? emb[row * E_ + k] : 0.f;
  unsigned short h = f2bf_rne(v);
  float hf = __uint_as_float((unsigned)h << 16);
  unsigned short lo = f2bf_rne(v - hf);
  Ahi[i] = (short)h;
  Alo[i] = (short)lo;
}

// ---------------------------------------------------------------------------
// proj = emb @ Wxp via bf16x3 split MFMA. K-loop = R7 single-buffer (dbuf was
// measured neutral in R11). NEW: coalesced C-write epilogue — each 128x128
// tile half (64 rows) is staged to LDS (float[64][132], unioned with the
// 32KB staging buffer -> same occupancy) then written as flat contiguous
// float4s (per instruction the WG commits 4KB contiguous vs the old 64B
// row-segment scatter of scalar stores; proj writes are 153.6 MB).
// Linear grid + bijective XCD swizzle (m204) kept.
// ---------------------------------------------------------------------------
__global__ __launch_bounds__(256) void gemm_mfma(
    const short* __restrict__ Ahi, const short* __restrict__ Alo,
    const short* __restrict__ Bthi, const short* __restrict__ Btlo,
    float* __restrict__ proj) {
  __shared__ __align__(16) char smem[64 * 132 * 4];   // 33792 B
  short* lds = (short*)smem;                          // K-loop view (32768 B)
  float (*ct)[132] = (float(*)[132])smem;             // epilogue view

  int tid = threadIdx.x, wid = tid >> 6, lane = tid & 63;

  // bijective XCD swizzle: nwg=2346, q=293, r=2
  int bid = blockIdx.x;
  int xcd = bid & 7, idx = bid >> 3;
  int wgid = (xcd < 2 ? xcd * 294 : 588 + (xcd - 2) * 293) + idx;
  int m0 = (wgid / 6) * 128;
  int n0 = (wgid % 6) * 128;

  f32x4 acc[4][4] = {};

  int lr = lane >> 2, lc = lane & 3;
  int q0 = wid * 2, q1 = q0 + 1;
  int r0 = q0 * 16 + lr, r1 = q1 * 16 + lr;
  int am0 = m0 + r0; if (am0 > V_ - 1) am0 = V_ - 1;
  int am1 = m0 + r1; if (am1 > V_ - 1) am1 = V_ - 1;
  size_t gaOff0 = (size_t)am0 * KP + lc * 8;
  size_t gaOff1 = (size_t)am1 * KP + lc * 8;
  size_t gbOff0 = (size_t)(n0 + r0) * KP + lc * 8;
  size_t gbOff1 = (size_t)(n0 + r1) * KP + lc * 8;

  int quad = lane >> 4;
  int arow = (wid >> 1) * 64 + (lane & 15);
  int brow = (wid & 1) * 64 + (lane & 15);

  for (int k0 = 0; k0 < KP; k0 += 32) {
    gload_lds16(Ahi  + gaOff0 + k0, lds +         q0 * 512);
    gload_lds16(Ahi  + gaOff1 + k0, lds +         q1 * 512);
    gload_lds16(Alo  + gaOff0 + k0, lds +  4096 + q0 * 512);
    gload_lds16(Alo  + gaOff1 + k0, lds +  4096 + q1 * 512);
    gload_lds16(Bthi + gbOff0 + k0, lds +  8192 + q0 * 512);
    gload_lds16(Bthi + gbOff1 + k0, lds +  8192 + q1 * 512);
    gload_lds16(Btlo + gbOff0 + k0, lds + 12288 + q0 * 512);
    gload_lds16(Btlo + gbOff1 + k0, lds + 12288 + q1 * 512);
    __syncthreads();

    bf16x8 ah[4], al[4], bh[4], bl[4];
#pragma unroll
    for (int i = 0; i < 4; ++i) {
      ah[i] = *(bf16x8*)&lds[        (arow + i*16) * 32 + quad * 8];
      al[i] = *(bf16x8*)&lds[ 4096 + (arow + i*16) * 32 + quad * 8];
      bh[i] = *(bf16x8*)&lds[ 8192 + (brow + i*16) * 32 + quad * 8];
      bl[i] = *(bf16x8*)&lds[12288 + (brow + i*16) * 32 + quad * 8];
    }
#pragma unroll
    for (int i = 0; i < 4; ++i)
#pragma unroll
      for (int j = 0; j < 4; ++j) {
        acc[i][j] = __builtin_amdgcn_mfma_f32_16x16x32_bf16(ah[i], bh[j], acc[i][j], 0, 0, 0);
        acc[i][j] = __builtin_amdgcn_mfma_f32_16x16x32_bf16(ah[i], bl[j], acc[i][j], 0, 0, 0);
        acc[i][j] = __builtin_amdgcn_mfma_f32_16x16x32_bf16(al[i], bh[j], acc[i][j], 0, 0, 0);
      }
    __syncthreads();
  }

  // --- coalesced epilogue: 2 half-tiles of 64 rows each ---
  int halfsel = wid >> 1;
  int lcol = (wid & 1) * 64 + (lane & 15);
#pragma unroll
  for (int hp = 0; hp < 2; ++hp) {
    if (hp) __syncthreads();          // ct reuse between halves
    if (halfsel == hp) {
#pragma unroll
      for (int i = 0; i < 4; ++i)
#pragma unroll
        for (int j = 0; j < 4; ++j)
#pragma unroll
          for (int r = 0; r < 4; ++r)
            ct[quad*4 + i*16 + r][lcol + j*16] = acc[i][j][r];
    }
    __syncthreads();                  // staging visible
#pragma unroll
    for (int q = 0; q < 8; ++q) {
      int f = tid + q * 256;          // flat float4 index 0..2047
      int row = f >> 5, c4 = f & 31;  // 32 float4 per row
      int gr = m0 + hp * 64 + row;
      if (gr < V_)
        *(float4*)(proj + (size_t)gr * NCOL + n0 + c4 * 4) =
            *(const float4*)&ct[row][c4 * 4];
    }
  }
}

// ---------------------------------------------------------------------------
// Recurrence: round-0 best-measured body VERBATIM (465 us — FROZEN).
// ---------------------------------------------------------------------------
__global__ __attribute__((amdgpu_flat_work_group_size(256, 256),
                          amdgpu_waves_per_eu(2, 2)))
void recur_kernel(
    const int* __restrict__ ctx, const int* __restrict__ endseq,
    const int* __restrict__ ctx_len, const int* __restrict__ end_len,
    const float* __restrict__ proj, const float* __restrict__ Uall,
    const float* __restrict__ bias, float* __restrict__ states) {
  __shared__ __align__(16) float h_s[128];
  __shared__ __align__(16) float rh_s[128];
  __shared__ __align__(16) float u_s[128];
  __shared__ __align__(16) float pg[8][260];
  __shared__ __align__(16) float pc[8][132];

  int bid = blockIdx.x;
  int tid = threadIdx.x;
  const int* seq; int S, L, b, dir; float* stbase;
  if (bid < 256) {
    b = bid >> 1; dir = bid & 1;
    seq = ctx + b * SC_; S = SC_; L = ctx_len[b];
    stbase = states + (dir ? SZ_ST_CTX : 0) + (size_t)b * SC_ * C_;
  } else {
    int q = bid - 256; b = q >> 1; dir = q & 1;
    seq = endseq + b * SE_; S = SE_; L = end_len[b];
    stbase = states + 2*SZ_ST_CTX + (dir ? SZ_ST_END : 0) + (size_t)b * SE_ * C_;
  }
  int dirOff = dir ? 384 : 0;
  int kg = tid >> 5, jg = tid & 31;

  float wg[16][8];
  float wc[16][4];
#pragma unroll
  for (int kk = 0; kk < 16; ++kk) {
    const float* up = Uall + (size_t)(kg*16 + kk) * NCOL + dirOff;
    float4 w0 = *(const float4*)(up + jg*8);
    float4 w1 = *(const float4*)(up + jg*8 + 4);
    wg[kk][0]=w0.x; wg[kk][1]=w0.y; wg[kk][2]=w0.z; wg[kk][3]=w0.w;
    wg[kk][4]=w1.x; wg[kk][5]=w1.y; wg[kk][6]=w1.z; wg[kk][7]=w1.w;
    float4 wv = *(const float4*)(up + 256 + jg*4);
    wc[kk][0]=wv.x; wc[kk][1]=wv.y; wc[kk][2]=wv.z; wc[kk][3]=wv.w;
  }
  float bias_g = bias[dirOff + tid];
  float bias_c = (tid < 128) ? bias[dirOff + 256 + tid] : 0.f;

  if (tid < 128) h_s[tid] = 0.f;
  __syncthreads();

  int pos0 = dir ? (L - 1) : 0;
  int tok0 = seq[pos0];
  const float* xr0 = proj + (size_t)tok0 * NCOL + dirOff;
  float xg = xr0[tid];
  float xc = (tid < 128) ? xr0[256 + tid] : 0.f;

  for (int t = 0; t < L; ++t) {
    float xg_n = 0.f, xc_n = 0.f;
    if (t + 1 < L) {
      int pos_n = dir ? (L - 2 - t) : (t + 1);
      int tok_n = seq[pos_n];
      const float* xr = proj + (size_t)tok_n * NCOL + dirOff;
      xg_n = xr[tid];
      xc_n = (tid < 128) ? xr[256 + tid] : 0.f;
    }

    float a[8] = {0.f,0.f,0.f,0.f,0.f,0.f,0.f,0.f};
    const float4* h4 = (const float4*)h_s;
#pragma unroll
    for (int q = 0; q < 4; ++q) {
      float4 hv = h4[kg*4 + q];
      float he[4] = {hv.x, hv.y, hv.z, hv.w};
#pragma unroll
      for (int e = 0; e < 4; ++e)
#pragma unroll
        for (int jj = 0; jj < 8; ++jj)
          a[jj] += he[e] * wg[q*4 + e][jj];
    }
    *(float4*)(&pg[kg][jg*8])     = make_float4(a[0], a[1], a[2], a[3]);
    *(float4*)(&pg[kg][jg*8 + 4]) = make_float4(a[4], a[5], a[6], a[7]);
    __syncthreads();   // B1

    float g = xg + bias_g;
#pragma unroll
    for (int k2 = 0; k2 < 8; ++k2) g += pg[k2][tid];
    g = fast_sigmoid(g);

    float h_old = 0.f;
    if (tid < 128) { h_old = h_s[tid]; rh_s[tid] = g * h_old; }
    else           { u_s[tid - 128] = g; }
    __syncthreads();   // B2

    float ac[4] = {0.f, 0.f, 0.f, 0.f};
    const float4* rh4 = (const float4*)rh_s;
#pragma unroll
    for (int q = 0; q < 4; ++q) {
      float4 rv = rh4[kg*4 + q];
      float re[4] = {rv.x, rv.y, rv.z, rv.w};
#pragma unroll
      for (int e = 0; e < 4; ++e)
#pragma unroll
        for (int jj = 0; jj < 4; ++jj)
          ac[jj] += re[e] * wc[q*4 + e][jj];
    }
    *(float4*)(&pc[kg][jg*4]) = make_float4(ac[0], ac[1], ac[2], ac[3]);
    __syncthreads();   // B3

    if (tid < 128) {
      float cs = xc + bias_c;
#pragma unroll
      for (int k2 = 0; k2 < 8; ++k2) cs += pc[k2][tid];
      float c = fast_tanh(cs);
      float u = u_s[tid];
      float hn = u * h_old + (1.f - u) * c;
      h_s[tid] = hn;
      int pos = dir ? (L - 1 - t) : t;
      stbase[(size_t)pos * C_ + tid] = hn;
    }
    __syncthreads();   // B4
    xg = xg_n; xc = xc_n;
  }

  for (int i = L * C_ + tid; i < S * C_; i += 256) stbase[i] = 0.f;
}

// ---------------------------------------------------------------------------
// Attention v3 (R7 winner, verbatim): SPLIT across chunk halves. ctx chains
// get 2 WGs (16 chunks each); end chains 1 WG. Grid 768, launch_bounds(256,3)
// -> 3 WG/CU. Each WG emits an online-softmax partial triple (m, l, acc[128])
// to the partials buffer; attn_merge combines per chain.
// ---------------------------------------------------------------------------
__global__ __launch_bounds__(256, 3) void attn_kernel(
    const float* __restrict__ states, const short* __restrict__ awt_hi,
    const short* __restrict__ awt_lo, const float* __restrict__ att_v,
    const float* __restrict__ att_b, float* __restrict__ partials) {
  __shared__ __align__(16) float st_s[16][132];
  __shared__ __align__(16) short ah_s[16][132];
  __shared__ __align__(16) short al_s[16][132];
  __shared__ float spart[4][16];
  __shared__ float score_s[16];
  __shared__ float cm[128], cl[128], ca[128];

  int bid = blockIdx.x, tid = threadIdx.x;
  int b, dir, S, pchain, ph, ch0, ch1, isEndWG; const float* stb;
  if (bid < 512) {            // ctx: 256 chains x 2 halves
    int chain = bid >> 1;  ph = bid & 1;
    b = chain >> 1; dir = chain & 1; S = SC_;
    stb = states + (dir ? SZ_ST_CTX : 0) + (size_t)b * SC_ * C_;
    pchain = chain; ch0 = ph * 16; ch1 = ch0 + 16; isEndWG = 0;
  } else {                    // end: 256 chains x 1 WG
    int e = bid - 512;
    b = e >> 1; dir = e & 1; S = SE_;
    stb = states + 2*SZ_ST_CTX + (dir ? SZ_ST_END : 0) + (size_t)b * SE_ * C_;
    pchain = 256 + e; ph = 0; ch0 = 0; ch1 = SE_ >> 4; isEndWG = 1;
  }
  (void)S;

  int w = tid >> 6, lane = tid & 63;
  int quad = lane >> 4, l15 = lane & 15;

  int d0 = 32 * w + l15, d1 = d0 + 16;
  bf16x8 bh0[4], bh1[4], bl0[4], bl1[4];
#pragma unroll
  for (int kt = 0; kt < 4; ++kt) {
    bh0[kt] = *(const bf16x8*)&awt_hi[d0*128 + kt*32 + quad*8];
    bh1[kt] = *(const bf16x8*)&awt_hi[d1*128 + kt*32 + quad*8];
    bl0[kt] = *(const bf16x8*)&awt_lo[d0*128 + kt*32 + quad*8];
    bl1[kt] = *(const bf16x8*)&awt_lo[d1*128 + kt*32 + quad*8];
  }
  float vv0 = att_v[d0], vv1 = att_v[d1];
  float bb0 = att_b[d0], bb1 = att_b[d1];

  int c = tid & 127, half = tid >> 7;
  float m = -1e30f, lsum = 0.f, acc = 0.f;

  int lrow = tid >> 4, lcol = (tid & 15) * 8;
  float4 p0, p1;
  {
    const float* src = stb + (size_t)(ch0 * 16 + lrow) * C_ + lcol;
    p0 = *(const float4*)(src);
    p1 = *(const float4*)(src + 4);
  }

  for (int ch = ch0; ch < ch1; ++ch) {
    __syncthreads();   // B0
    float f[8] = {p0.x, p0.y, p0.z, p0.w, p1.x, p1.y, p1.z, p1.w};
    short hi8[8], lo8[8];
#pragma unroll
    for (int j = 0; j < 8; ++j) {
      unsigned short h = f2bf_rne(f[j]);
      float hf = __uint_as_float((unsigned)h << 16);
      hi8[j] = (short)h;
      lo8[j] = (short)f2bf_rne(f[j] - hf);
    }
    *(float4*)(&st_s[lrow][lcol])     = p0;
    *(float4*)(&st_s[lrow][lcol + 4]) = p1;
    *(bf16x8*)(&ah_s[lrow][lcol]) = *(bf16x8*)hi8;
    *(bf16x8*)(&al_s[lrow][lcol]) = *(bf16x8*)lo8;
    if (ch + 1 < ch1) {
      const float* src = stb + (size_t)((ch + 1) * 16 + lrow) * C_ + lcol;
      p0 = *(const float4*)(src);
      p1 = *(const float4*)(src + 4);
    }
    __syncthreads();   // B1

    f32x4 ac0 = {0.f, 0.f, 0.f, 0.f}, ac1 = {0.f, 0.f, 0.f, 0.f};
#pragma unroll
    for (int kt = 0; kt < 4; ++kt) {
      bf16x8 a_hi = *(bf16x8*)&ah_s[l15][kt*32 + quad*8];
      bf16x8 a_lo = *(bf16x8*)&al_s[l15][kt*32 + quad*8];
      ac0 = __builtin_amdgcn_mfma_f32_16x16x32_bf16(a_hi, bh0[kt], ac0, 0, 0, 0);
      ac0 = __builtin_amdgcn_mfma_f32_16x16x32_bf16(a_hi, bl0[kt], ac0, 0, 0, 0);
      ac0 = __builtin_amdgcn_mfma_f32_16x16x32_bf16(a_lo, bh0[kt], ac0, 0, 0, 0);
      ac1 = __builtin_amdgcn_mfma_f32_16x16x32_bf16(a_hi, bh1[kt], ac1, 0, 0, 0);
      ac1 = __builtin_amdgcn_mfma_f32_16x16x32_bf16(a_hi, bl1[kt], ac1, 0, 0, 0);
      ac1 = __builtin_amdgcn_mfma_f32_16x16x32_bf16(a_lo, bh1[kt], ac1, 0, 0, 0);
    }

    float part[4];
#pragma unroll
    for (int r = 0; r < 4; ++r)
      part[r] = fast_tanh(ac0[r] + bb0) * vv0 + fast_tanh(ac1[r] + bb1) * vv1;
#pragma unroll
    for (int mask = 1; mask <= 8; mask <<= 1)
#pragma unroll
      for (int r = 0; r < 4; ++r)
        part[r] += __shfl_xor(part[r], mask, 64);
    if (l15 == 0) {
#pragma unroll
      for (int r = 0; r < 4; ++r) spart[w][quad*4 + r] = part[r];
    }
    __syncthreads();   // B2
    if (tid < 16)
      score_s[tid] = spart[0][tid] + spart[1][tid] + spart[2][tid] + spart[3][tid];
    __syncthreads();   // B3

    float srow[8]; float smax = m;
#pragma unroll
    for (int r = 0; r < 8; ++r) { srow[r] = score_s[half*8 + r]; smax = fmaxf(smax, srow[r]); }
    float scale = __expf(m - smax);
    acc *= scale; lsum *= scale; m = smax;
#pragma unroll
    for (int r = 0; r < 8; ++r) {
      float wgt = __expf(srow[r] - m);
      lsum += wgt;
      acc += wgt * st_s[half*8 + r][c];
    }
  }

  __syncthreads();
  if (half == 1) { cm[c] = m; cl[c] = lsum; ca[c] = acc; }
  __syncthreads();
  if (half == 0) {
    float m1 = cm[c], l1 = cl[c], a1 = ca[c];
    float M = fmaxf(m, m1);
    float w0 = __expf(m - M), w1 = __expf(m1 - M);
    float Lt = lsum * w0 + l1 * w1;
    float At = acc * w0 + a1 * w1;
    float* p = partials + ((size_t)pchain * 2 + ph) * 130;
    if (c == 0) { p[0] = M; p[1] = Lt; }
    p[2 + c] = At;
    if (isEndWG) {   // neutral second half so merge is uniform
      float* pn = partials + ((size_t)pchain * 2 + 1) * 130;
      if (c == 0) { pn[0] = -1e30f; pn[1] = 0.f; }
      pn[2 + c] = 0.f;
    }
  }
}

// Combine the two partial triples of each chain into feats.
__global__ __launch_bounds__(128) void attn_merge_kernel(
    const float* __restrict__ partials, float* __restrict__ feats) {
  int q = blockIdx.x, c = threadIdx.x;
  const float* p0 = partials + (size_t)q * 2 * 130;
  const float* p1 = p0 + 130;
  float m0 = p0[0], l0 = p0[1], a0 = p0[2 + c];
  float m1 = p1[0], l1 = p1[1], a1 = p1[2 + c];
  float M = fmaxf(m0, m1);
  float w0 = __expf(m0 - M), w1 = __expf(m1 - M);
  int b, off;
  if (q < 256) { b = q >> 1; off = (q & 1) * 128; }
  else { int e = q - 256; b = e >> 1; off = 256 + (e & 1) * 128; }
  feats[b * 512 + off + c] = (a0 * w0 + a1 * w1) / (l0 * w0 + l1 * w1);
}

// ---------------------------------------------------------------------------
// Head
// ---------------------------------------------------------------------------
__global__ __launch_bounds__(128) void head_kernel(
    const float* __restrict__ feats, const float* __restrict__ hid_w,
    const float* __restrict__ hid_b, const float* __restrict__ out_w,
    const float* __restrict__ out_b, float* __restrict__ out) {
  __shared__ __align__(16) float f_s[512];
  __shared__ float part[2];
  int b = blockIdx.x, tid = threadIdx.x;
  for (int i = tid; i < 512; i += 128) f_s[i] = feats[b * 512 + i];
  __syncthreads();
  float h = hid_b[tid];
  for (int k = 0; k < 512; ++k) h += f_s[k] * hid_w[k * 128 + tid];
  h = fmaxf(h, 0.f);
  float p = h * out_w[tid];
#pragma unroll
  for (int off = 32; off > 0; off >>= 1) p += __shfl_xor(p, off, 64);
  if ((tid & 63) == 0) part[tid >> 6] = p;
  __syncthreads();
  if (tid == 0) out[b] = part[0] + part[1] + out_b[0];
}

// ---------------------------------------------------------------------------
extern "C" void kernel_launch(void* const* d_in, const int* in_sizes, int n_in,
                              void* d_out, int out_size, void* d_ws, size_t ws_size,
                              hipStream_t stream) {
  const int*   ctx     = (const int*)d_in[0];
  const int*   endseq  = (const int*)d_in[1];
  const int*   ctx_len = (const int*)d_in[2];
  const int*   end_len = (const int*)d_in[3];
  const float* emb     = (const float*)d_in[4];
  const float* fw_gw   = (const float*)d_in[5];
  const float* fw_gb   = (const float*)d_in[6];
  const float* fw_cw   = (const float*)d_in[7];
  const float* fw_cb   = (const float*)d_in[8];
  const float* bw_gw   = (const float*)d_in[9];
  const float* bw_gb   = (const float*)d_in[10];
  const float* bw_cw   = (const float*)d_in[11];
  const float* bw_cb   = (const float*)d_in[12];
  const float* att_v   = (const float*)d_in[13];
  const float* att_w   = (const float*)d_in[14];
  const float* att_b   = (const float*)d_in[15];
  const float* hid_w   = (const float*)d_in[16];
  const float* hid_b   = (const float*)d_in[17];
  const float* out_w   = (const float*)d_in[18];
  const float* out_b   = (const float*)d_in[19];
  float* ws  = (float*)d_ws;
  float* out = (float*)d_out;

  short* Ahi    = (short*)(ws + OFF_ST);
  short* Alo    = Ahi + (size_t)V_ * KP;
  short* Bthi   = (short*)(ws + OFF_BT);
  short* Btlo   = Bthi + (size_t)NCOL * KP;
  short* awt_hi = (short*)(ws + OFF_AWT);
  short* awt_lo = awt_hi + 128 * 128;
  float* partials = ws + OFF_BT;   // Bt region is dead after gemm

  pack_misc<<<1411, 256, 0, stream>>>(fw_gw, fw_gb, fw_cw, fw_cb,
                                      bw_gw, bw_gb, bw_cw, bw_cb, att_w,
                                      ws + OFF_UALL, ws + OFF_BIAS,
                                      Bthi, Btlo, awt_hi, awt_lo);
  pack_emb<<<(int)(((size_t)V_ * KP + 255) / 256), 256, 0, stream>>>(emb, Ahi, Alo);

  gemm_mfma<<<2346, 256, 0, stream>>>(Ahi, Alo, Bthi, Btlo, ws + OFF_PROJ);

  recur_kernel<<<512, 256, 0, stream>>>(ctx, endseq, ctx_len, end_len,
                                        ws + OFF_PROJ, ws + OFF_UALL,
                                        ws + OFF_BIAS, ws + OFF_ST);

  attn_kernel<<<768, 256, 0, stream>>>(ws + OFF_ST, awt_hi, awt_lo,
                                       att_v, att_b, partials);
  attn_merge_kernel<<<512, 128, 0, stream>>>(partials, ws + OFF_FEATS);

  head_kernel<<<128, 128, 0, stream>>>(ws + OFF_FEATS, hid_w, hid_b,
                                       out_w, out_b, out);
}

// Round 14
// 733.049 us; speedup vs baseline: 1.0321x; 1.0321x over previous
//
#include <hip/hip_runtime.h>
#include <cstdint>
#include <cmath>

// Problem constants
static constexpr int V_  = 50000;
static constexpr int E_  = 300;
static constexpr int C_  = 128;
static constexpr int B_  = 128;
static constexpr int SC_ = 512;
static constexpr int SE_ = 64;
static constexpr int NCOL = 768;   // [fw_gate 256 | fw_cand 128 | bw_gate 256 | bw_cand 128]
static constexpr int KP  = 320;    // K padded to 10 x 32 for MFMA

// ws layout (float offsets)
static constexpr size_t OFF_PROJ  = 0;
static constexpr size_t SZ_PROJ   = (size_t)V_ * NCOL;
static constexpr size_t OFF_WXP   = OFF_PROJ + SZ_PROJ;   // unused (kept for layout stability)
static constexpr size_t SZ_WXP    = (size_t)304 * NCOL;
static constexpr size_t OFF_UALL  = OFF_WXP + SZ_WXP;
static constexpr size_t SZ_UALL   = (size_t)C_ * NCOL;
static constexpr size_t OFF_BIAS  = OFF_UALL + SZ_UALL;
static constexpr size_t SZ_BIAS   = NCOL;
static constexpr size_t OFF_ST    = OFF_BIAS + SZ_BIAS;
static constexpr size_t SZ_ST_CTX = (size_t)B_ * SC_ * C_;
static constexpr size_t SZ_ST_END = (size_t)B_ * SE_ * C_;
static constexpr size_t SZ_ST     = 2*SZ_ST_CTX + 2*SZ_ST_END;    // 75.5 MB
static constexpr size_t OFF_FEATS = OFF_ST + SZ_ST;
static constexpr size_t SZ_FEATS  = (size_t)B_ * 512;
static constexpr size_t OFF_BT    = OFF_FEATS + SZ_FEATS;
static constexpr size_t SZ_BT     = (size_t)NCOL * KP / 2 * 2;    // 2 short arrays (245760 floats)
static constexpr size_t OFF_AWT   = OFF_BT + SZ_BT;               // att_w^T hi/lo shorts
// Partials buffer for split attention REUSES the Bt region (dead after gemm):
// 512 chains x 2 halves x (m, l, acc[128]) = 133120 floats < 245760.
// A_hi/A_lo (bf16) OVERLAP the states region (dead once gemm ends; recur
// zeroes its own tail rows so no global memset is needed).

typedef __attribute__((ext_vector_type(8))) short bf16x8;
typedef __attribute__((ext_vector_type(4))) float f32x4;

static __device__ __forceinline__ unsigned short f2bf_rne(float f) {
  unsigned u = __float_as_uint(f);
  unsigned r = u + 0x7fffu + ((u >> 16) & 1u);
  return (unsigned short)(r >> 16);
}

static __device__ __forceinline__ void gload_lds16(const short* g, short* l) {
  __builtin_amdgcn_global_load_lds(
      (const __attribute__((address_space(1))) void*)g,
      (__attribute__((address_space(3))) void*)l, 16, 0, 0);
}

// fast activations: __expf + v_rcp_f32 (~1e-6 rel err; logit threshold 7.4e-5)
static __device__ __forceinline__ float fast_sigmoid(float x) {
  return __builtin_amdgcn_rcpf(1.f + __expf(-x));
}
static __device__ __forceinline__ float fast_tanh(float x) {
  return fmaf(-2.f, __builtin_amdgcn_rcpf(__expf(2.f * x) + 1.f), 1.f);
}

// ---------------------------------------------------------------------------
// pack_misc (R12, proven numerically identical): Bt hi/lo DIRECT from raw
// weights (no Wxp intermediate), att_w^T hi/lo, Uall[128][768], bias[768]
// in ONE dispatch — removes the pack_kernel->pack_bt serialization.
// ---------------------------------------------------------------------------
__global__ void pack_misc(const float* __restrict__ fw_gw, const float* __restrict__ fw_gb,
                          const float* __restrict__ fw_cw, const float* __restrict__ fw_cb,
                          const float* __restrict__ bw_gw, const float* __restrict__ bw_gb,
                          const float* __restrict__ bw_cw, const float* __restrict__ bw_cb,
                          const float* __restrict__ att_w,
                          float* __restrict__ Uall, float* __restrict__ bias,
                          short* __restrict__ Bthi, short* __restrict__ Btlo,
                          short* __restrict__ awt_hi, short* __restrict__ awt_lo) {
  int i = blockIdx.x * 256 + threadIdx.x;
  if (i < NCOL * KP) {
    int k = i % KP, n = i / KP;
    float v = 0.f;
    if (k < 300) {
      if (n < 256)      v = fw_gw[k*256 + n];
      else if (n < 384) v = fw_cw[k*128 + (n-256)];
      else if (n < 640) v = bw_gw[k*256 + (n-384)];
      else              v = bw_cw[k*128 + (n-640)];
    }
    unsigned short h = f2bf_rne(v);
    float hf = __uint_as_float((unsigned)h << 16);
    Bthi[i] = (short)h;
    Btlo[i] = (short)f2bf_rne(v - hf);
    return;
  }
  int j = i - NCOL * KP;
  if (j < 128 * 128) {
    int d = j >> 7, c = j & 127;
    float v = att_w[(size_t)c * 128 + d];   // transpose: awt[d][k=c]
    unsigned short h = f2bf_rne(v);
    float hf = __uint_as_float((unsigned)h << 16);
    awt_hi[j] = (short)h;
    awt_lo[j] = (short)f2bf_rne(v - hf);
    return;
  }
  j -= 128 * 128;
  if (j < 128 * NCOL) {
    int k = j / NCOL, c = j % NCOL;
    int kk = 300 + k;
    float v;
    if (c < 256)      v = fw_gw[kk*256 + c];
    else if (c < 384) v = fw_cw[kk*128 + (c-256)];
    else if (c < 640) v = bw_gw[kk*256 + (c-384)];
    else              v = bw_cw[kk*128 + (c-640)];
    Uall[j] = v;
    return;
  }
  j -= 128 * NCOL;
  if (j < NCOL) {
    float v;
    if (j < 256)      v = fw_gb[j];
    else if (j < 384) v = fw_cb[j-256];
    else if (j < 640) v = bw_gb[j-384];
    else              v = bw_cb[j-640];
    bias[j] = v;
  }
}

__global__ void pack_emb(const float* __restrict__ emb, short* __restrict__ Ahi,
                         short* __restrict__ Alo) {
  size_t i = (size_t)blockIdx.x * 256 + threadIdx.x;
  if (i >= (size_t)V_ * KP) return;
  int k = (int)(i % KP);
  size_t row = i / KP;
  float v = (k < E_) ? emb[row * E_ + k] : 0.f;
  unsigned short h = f2bf_rne(v);
  float hf = __uint_as_float((unsigned)h << 16);
  unsigned short lo = f2bf_rne(v - hf);
  Ahi[i] = (short)h;
  Alo[i] = (short)lo;
}

// ---------------------------------------------------------------------------
// proj = emb @ Wxp via bf16x3 split MFMA. R11 best-measured form: double-
// buffered K-loop with issue-early staging, ORIGINAL scatter C-write (R12's
// staged epilogue regressed — extra barriers cost more than 64B-scatter).
// Linear grid + bijective XCD swizzle (m204).
// ---------------------------------------------------------------------------
__global__ __launch_bounds__(256) void gemm_mfma(
    const short* __restrict__ Ahi, const short* __restrict__ Alo,
    const short* __restrict__ Bthi, const short* __restrict__ Btlo,
    float* __restrict__ proj) {
  __shared__ short lds[2][16384];
  int tid = threadIdx.x, wid = tid >> 6, lane = tid & 63;

  // bijective XCD swizzle: nwg=2346, q=293, r=2
  int bid = blockIdx.x;
  int xcd = bid & 7, idx = bid >> 3;
  int wgid = (xcd < 2 ? xcd * 294 : 588 + (xcd - 2) * 293) + idx;
  int m0 = (wgid / 6) * 128;
  int n0 = (wgid % 6) * 128;

  f32x4 acc[4][4] = {};

  int lr = lane >> 2, lc = lane & 3;
  int q0 = wid * 2, q1 = q0 + 1;
  int r0 = q0 * 16 + lr, r1 = q1 * 16 + lr;
  int am0 = m0 + r0; if (am0 > V_ - 1) am0 = V_ - 1;
  int am1 = m0 + r1; if (am1 > V_ - 1) am1 = V_ - 1;
  size_t gaOff0 = (size_t)am0 * KP + lc * 8;
  size_t gaOff1 = (size_t)am1 * KP + lc * 8;
  size_t gbOff0 = (size_t)(n0 + r0) * KP + lc * 8;
  size_t gbOff1 = (size_t)(n0 + r1) * KP + lc * 8;

  int quad = lane >> 4;
  int arow = (wid >> 1) * 64 + (lane & 15);
  int brow = (wid & 1) * 64 + (lane & 15);

#define GEMM_STAGE(BUF, K0)                                          \
  do {                                                               \
    gload_lds16(Ahi  + gaOff0 + (K0), &lds[BUF][        q0 * 512]);  \
    gload_lds16(Ahi  + gaOff1 + (K0), &lds[BUF][        q1 * 512]);  \
    gload_lds16(Alo  + gaOff0 + (K0), &lds[BUF][ 4096 + q0 * 512]);  \
    gload_lds16(Alo  + gaOff1 + (K0), &lds[BUF][ 4096 + q1 * 512]);  \
    gload_lds16(Bthi + gbOff0 + (K0), &lds[BUF][ 8192 + q0 * 512]);  \
    gload_lds16(Bthi + gbOff1 + (K0), &lds[BUF][ 8192 + q1 * 512]);  \
    gload_lds16(Btlo + gbOff0 + (K0), &lds[BUF][12288 + q0 * 512]);  \
    gload_lds16(Btlo + gbOff1 + (K0), &lds[BUF][12288 + q1 * 512]);  \
  } while (0)

  GEMM_STAGE(0, 0);
  __syncthreads();   // prologue drain: buf0 ready

  for (int it = 0; it < KP / 32; ++it) {
    int cur = it & 1;
    if (it + 1 < KP / 32) GEMM_STAGE(cur ^ 1, (it + 1) * 32);  // issue EARLY

    bf16x8 ah[4], al[4], bh[4], bl[4];
#pragma unroll
    for (int i = 0; i < 4; ++i) {
      ah[i] = *(bf16x8*)&lds[cur][        (arow + i*16) * 32 + quad * 8];
      al[i] = *(bf16x8*)&lds[cur][ 4096 + (arow + i*16) * 32 + quad * 8];
      bh[i] = *(bf16x8*)&lds[cur][ 8192 + (brow + i*16) * 32 + quad * 8];
      bl[i] = *(bf16x8*)&lds[cur][12288 + (brow + i*16) * 32 + quad * 8];
    }
#pragma unroll
    for (int i = 0; i < 4; ++i)
#pragma unroll
      for (int j = 0; j < 4; ++j) {
        acc[i][j] = __builtin_amdgcn_mfma_f32_16x16x32_bf16(ah[i], bh[j], acc[i][j], 0, 0, 0);
        acc[i][j] = __builtin_amdgcn_mfma_f32_16x16x32_bf16(ah[i], bl[j], acc[i][j], 0, 0, 0);
        acc[i][j] = __builtin_amdgcn_mfma_f32_16x16x32_bf16(al[i], bh[j], acc[i][j], 0, 0, 0);
      }
    __syncthreads();   // drains next-tile loads (had full MFMA phase to land)
  }
#undef GEMM_STAGE

  int colb = n0 + (wid & 1) * 64 + (lane & 15);
  int rowb = m0 + (wid >> 1) * 64 + quad * 4;
#pragma unroll
  for (int i = 0; i < 4; ++i) {
    int rb = rowb + i * 16;
#pragma unroll
    for (int j = 0; j < 4; ++j) {
      int cc = colb + j * 16;
#pragma unroll
      for (int r = 0; r < 4; ++r) {
        int rr = rb + r;
        if (rr < V_) proj[(size_t)rr * NCOL + cc] = acc[i][j][r];
      }
    }
  }
}

// ---------------------------------------------------------------------------
// Recurrence: round-0 best-measured body VERBATIM (465 us — FROZEN).
// ---------------------------------------------------------------------------
__global__ __attribute__((amdgpu_flat_work_group_size(256, 256),
                          amdgpu_waves_per_eu(2, 2)))
void recur_kernel(
    const int* __restrict__ ctx, const int* __restrict__ endseq,
    const int* __restrict__ ctx_len, const int* __restrict__ end_len,
    const float* __restrict__ proj, const float* __restrict__ Uall,
    const float* __restrict__ bias, float* __restrict__ states) {
  __shared__ __align__(16) float h_s[128];
  __shared__ __align__(16) float rh_s[128];
  __shared__ __align__(16) float u_s[128];
  __shared__ __align__(16) float pg[8][260];
  __shared__ __align__(16) float pc[8][132];

  int bid = blockIdx.x;
  int tid = threadIdx.x;
  const int* seq; int S, L, b, dir; float* stbase;
  if (bid < 256) {
    b = bid >> 1; dir = bid & 1;
    seq = ctx + b * SC_; S = SC_; L = ctx_len[b];
    stbase = states + (dir ? SZ_ST_CTX : 0) + (size_t)b * SC_ * C_;
  } else {
    int q = bid - 256; b = q >> 1; dir = q & 1;
    seq = endseq + b * SE_; S = SE_; L = end_len[b];
    stbase = states + 2*SZ_ST_CTX + (dir ? SZ_ST_END : 0) + (size_t)b * SE_ * C_;
  }
  int dirOff = dir ? 384 : 0;
  int kg = tid >> 5, jg = tid & 31;

  float wg[16][8];
  float wc[16][4];
#pragma unroll
  for (int kk = 0; kk < 16; ++kk) {
    const float* up = Uall + (size_t)(kg*16 + kk) * NCOL + dirOff;
    float4 w0 = *(const float4*)(up + jg*8);
    float4 w1 = *(const float4*)(up + jg*8 + 4);
    wg[kk][0]=w0.x; wg[kk][1]=w0.y; wg[kk][2]=w0.z; wg[kk][3]=w0.w;
    wg[kk][4]=w1.x; wg[kk][5]=w1.y; wg[kk][6]=w1.z; wg[kk][7]=w1.w;
    float4 wv = *(const float4*)(up + 256 + jg*4);
    wc[kk][0]=wv.x; wc[kk][1]=wv.y; wc[kk][2]=wv.z; wc[kk][3]=wv.w;
  }
  float bias_g = bias[dirOff + tid];
  float bias_c = (tid < 128) ? bias[dirOff + 256 + tid] : 0.f;

  if (tid < 128) h_s[tid] = 0.f;
  __syncthreads();

  int pos0 = dir ? (L - 1) : 0;
  int tok0 = seq[pos0];
  const float* xr0 = proj + (size_t)tok0 * NCOL + dirOff;
  float xg = xr0[tid];
  float xc = (tid < 128) ? xr0[256 + tid] : 0.f;

  for (int t = 0; t < L; ++t) {
    float xg_n = 0.f, xc_n = 0.f;
    if (t + 1 < L) {
      int pos_n = dir ? (L - 2 - t) : (t + 1);
      int tok_n = seq[pos_n];
      const float* xr = proj + (size_t)tok_n * NCOL + dirOff;
      xg_n = xr[tid];
      xc_n = (tid < 128) ? xr[256 + tid] : 0.f;
    }

    float a[8] = {0.f,0.f,0.f,0.f,0.f,0.f,0.f,0.f};
    const float4* h4 = (const float4*)h_s;
#pragma unroll
    for (int q = 0; q < 4; ++q) {
      float4 hv = h4[kg*4 + q];
      float he[4] = {hv.x, hv.y, hv.z, hv.w};
#pragma unroll
      for (int e = 0; e < 4; ++e)
#pragma unroll
        for (int jj = 0; jj < 8; ++jj)
          a[jj] += he[e] * wg[q*4 + e][jj];
    }
    *(float4*)(&pg[kg][jg*8])     = make_float4(a[0], a[1], a[2], a[3]);
    *(float4*)(&pg[kg][jg*8 + 4]) = make_float4(a[4], a[5], a[6], a[7]);
    __syncthreads();   // B1

    float g = xg + bias_g;
#pragma unroll
    for (int k2 = 0; k2 < 8; ++k2) g += pg[k2][tid];
    g = fast_sigmoid(g);

    float h_old = 0.f;
    if (tid < 128) { h_old = h_s[tid]; rh_s[tid] = g * h_old; }
    else           { u_s[tid - 128] = g; }
    __syncthreads();   // B2

    float ac[4] = {0.f, 0.f, 0.f, 0.f};
    const float4* rh4 = (const float4*)rh_s;
#pragma unroll
    for (int q = 0; q < 4; ++q) {
      float4 rv = rh4[kg*4 + q];
      float re[4] = {rv.x, rv.y, rv.z, rv.w};
#pragma unroll
      for (int e = 0; e < 4; ++e)
#pragma unroll
        for (int jj = 0; jj < 4; ++jj)
          ac[jj] += re[e] * wc[q*4 + e][jj];
    }
    *(float4*)(&pc[kg][jg*4]) = make_float4(ac[0], ac[1], ac[2], ac[3]);
    __syncthreads();   // B3

    if (tid < 128) {
      float cs = xc + bias_c;
#pragma unroll
      for (int k2 = 0; k2 < 8; ++k2) cs += pc[k2][tid];
      float c = fast_tanh(cs);
      float u = u_s[tid];
      float hn = u * h_old + (1.f - u) * c;
      h_s[tid] = hn;
      int pos = dir ? (L - 1 - t) : t;
      stbase[(size_t)pos * C_ + tid] = hn;
    }
    __syncthreads();   // B4
    xg = xg_n; xc = xc_n;
  }

  for (int i = L * C_ + tid; i < S * C_; i += 256) stbase[i] = 0.f;
}

// ---------------------------------------------------------------------------
// Attention v3 (R7 winner, verbatim): SPLIT across chunk halves. ctx chains
// get 2 WGs (16 chunks each); end chains 1 WG. Grid 768, launch_bounds(256,3)
// -> 3 WG/CU. Each WG emits an online-softmax partial triple (m, l, acc[128])
// to the partials buffer; attn_merge combines per chain.
// ---------------------------------------------------------------------------
__global__ __launch_bounds__(256, 3) void attn_kernel(
    const float* __restrict__ states, const short* __restrict__ awt_hi,
    const short* __restrict__ awt_lo, const float* __restrict__ att_v,
    const float* __restrict__ att_b, float* __restrict__ partials) {
  __shared__ __align__(16) float st_s[16][132];
  __shared__ __align__(16) short ah_s[16][132];
  __shared__ __align__(16) short al_s[16][132];
  __shared__ float spart[4][16];
  __shared__ float score_s[16];
  __shared__ float cm[128], cl[128], ca[128];

  int bid = blockIdx.x, tid = threadIdx.x;
  int b, dir, S, pchain, ph, ch0, ch1, isEndWG; const float* stb;
  if (bid < 512) {            // ctx: 256 chains x 2 halves
    int chain = bid >> 1;  ph = bid & 1;
    b = chain >> 1; dir = chain & 1; S = SC_;
    stb = states + (dir ? SZ_ST_CTX : 0) + (size_t)b * SC_ * C_;
    pchain = chain; ch0 = ph * 16; ch1 = ch0 + 16; isEndWG = 0;
  } else {                    // end: 256 chains x 1 WG
    int e = bid - 512;
    b = e >> 1; dir = e & 1; S = SE_;
    stb = states + 2*SZ_ST_CTX + (dir ? SZ_ST_END : 0) + (size_t)b * SE_ * C_;
    pchain = 256 + e; ph = 0; ch0 = 0; ch1 = SE_ >> 4; isEndWG = 1;
  }
  (void)S;

  int w = tid >> 6, lane = tid & 63;
  int quad = lane >> 4, l15 = lane & 15;

  int d0 = 32 * w + l15, d1 = d0 + 16;
  bf16x8 bh0[4], bh1[4], bl0[4], bl1[4];
#pragma unroll
  for (int kt = 0; kt < 4; ++kt) {
    bh0[kt] = *(const bf16x8*)&awt_hi[d0*128 + kt*32 + quad*8];
    bh1[kt] = *(const bf16x8*)&awt_hi[d1*128 + kt*32 + quad*8];
    bl0[kt] = *(const bf16x8*)&awt_lo[d0*128 + kt*32 + quad*8];
    bl1[kt] = *(const bf16x8*)&awt_lo[d1*128 + kt*32 + quad*8];
  }
  float vv0 = att_v[d0], vv1 = att_v[d1];
  float bb0 = att_b[d0], bb1 = att_b[d1];

  int c = tid & 127, half = tid >> 7;
  float m = -1e30f, lsum = 0.f, acc = 0.f;

  int lrow = tid >> 4, lcol = (tid & 15) * 8;
  float4 p0, p1;
  {
    const float* src = stb + (size_t)(ch0 * 16 + lrow) * C_ + lcol;
    p0 = *(const float4*)(src);
    p1 = *(const float4*)(src + 4);
  }

  for (int ch = ch0; ch < ch1; ++ch) {
    __syncthreads();   // B0
    float f[8] = {p0.x, p0.y, p0.z, p0.w, p1.x, p1.y, p1.z, p1.w};
    short hi8[8], lo8[8];
#pragma unroll
    for (int j = 0; j < 8; ++j) {
      unsigned short h = f2bf_rne(f[j]);
      float hf = __uint_as_float((unsigned)h << 16);
      hi8[j] = (short)h;
      lo8[j] = (short)f2bf_rne(f[j] - hf);
    }
    *(float4*)(&st_s[lrow][lcol])     = p0;
    *(float4*)(&st_s[lrow][lcol + 4]) = p1;
    *(bf16x8*)(&ah_s[lrow][lcol]) = *(bf16x8*)hi8;
    *(bf16x8*)(&al_s[lrow][lcol]) = *(bf16x8*)lo8;
    if (ch + 1 < ch1) {
      const float* src = stb + (size_t)((ch + 1) * 16 + lrow) * C_ + lcol;
      p0 = *(const float4*)(src);
      p1 = *(const float4*)(src + 4);
    }
    __syncthreads();   // B1

    f32x4 ac0 = {0.f, 0.f, 0.f, 0.f}, ac1 = {0.f, 0.f, 0.f, 0.f};
#pragma unroll
    for (int kt = 0; kt < 4; ++kt) {
      bf16x8 a_hi = *(bf16x8*)&ah_s[l15][kt*32 + quad*8];
      bf16x8 a_lo = *(bf16x8*)&al_s[l15][kt*32 + quad*8];
      ac0 = __builtin_amdgcn_mfma_f32_16x16x32_bf16(a_hi, bh0[kt], ac0, 0, 0, 0);
      ac0 = __builtin_amdgcn_mfma_f32_16x16x32_bf16(a_hi, bl0[kt], ac0, 0, 0, 0);
      ac0 = __builtin_amdgcn_mfma_f32_16x16x32_bf16(a_lo, bh0[kt], ac0, 0, 0, 0);
      ac1 = __builtin_amdgcn_mfma_f32_16x16x32_bf16(a_hi, bh1[kt], ac1, 0, 0, 0);
      ac1 = __builtin_amdgcn_mfma_f32_16x16x32_bf16(a_hi, bl1[kt], ac1, 0, 0, 0);
      ac1 = __builtin_amdgcn_mfma_f32_16x16x32_bf16(a_lo, bh1[kt], ac1, 0, 0, 0);
    }

    float part[4];
#pragma unroll
    for (int r = 0; r < 4; ++r)
      part[r] = fast_tanh(ac0[r] + bb0) * vv0 + fast_tanh(ac1[r] + bb1) * vv1;
#pragma unroll
    for (int mask = 1; mask <= 8; mask <<= 1)
#pragma unroll
      for (int r = 0; r < 4; ++r)
        part[r] += __shfl_xor(part[r], mask, 64);
    if (l15 == 0) {
#pragma unroll
      for (int r = 0; r < 4; ++r) spart[w][quad*4 + r] = part[r];
    }
    __syncthreads();   // B2
    if (tid < 16)
      score_s[tid] = spart[0][tid] + spart[1][tid] + spart[2][tid] + spart[3][tid];
    __syncthreads();   // B3

    float srow[8]; float smax = m;
#pragma unroll
    for (int r = 0; r < 8; ++r) { srow[r] = score_s[half*8 + r]; smax = fmaxf(smax, srow[r]); }
    float scale = __expf(m - smax);
    acc *= scale; lsum *= scale; m = smax;
#pragma unroll
    for (int r = 0; r < 8; ++r) {
      float wgt = __expf(srow[r] - m);
      lsum += wgt;
      acc += wgt * st_s[half*8 + r][c];
    }
  }

  __syncthreads();
  if (half == 1) { cm[c] = m; cl[c] = lsum; ca[c] = acc; }
  __syncthreads();
  if (half == 0) {
    float m1 = cm[c], l1 = cl[c], a1 = ca[c];
    float M = fmaxf(m, m1);
    float w0 = __expf(m - M), w1 = __expf(m1 - M);
    float Lt = lsum * w0 + l1 * w1;
    float At = acc * w0 + a1 * w1;
    float* p = partials + ((size_t)pchain * 2 + ph) * 130;
    if (c == 0) { p[0] = M; p[1] = Lt; }
    p[2 + c] = At;
    if (isEndWG) {   // neutral second half so merge is uniform
      float* pn = partials + ((size_t)pchain * 2 + 1) * 130;
      if (c == 0) { pn[0] = -1e30f; pn[1] = 0.f; }
      pn[2 + c] = 0.f;
    }
  }
}

// Combine the two partial triples of each chain into feats.
__global__ __launch_bounds__(128) void attn_merge_kernel(
    const float* __restrict__ partials, float* __restrict__ feats) {
  int q = blockIdx.x, c = threadIdx.x;
  const float* p0 = partials + (size_t)q * 2 * 130;
  const float* p1 = p0 + 130;
  float m0 = p0[0], l0 = p0[1], a0 = p0[2 + c];
  float m1 = p1[0], l1 = p1[1], a1 = p1[2 + c];
  float M = fmaxf(m0, m1);
  float w0 = __expf(m0 - M), w1 = __expf(m1 - M);
  int b, off;
  if (q < 256) { b = q >> 1; off = (q & 1) * 128; }
  else { int e = q - 256; b = e >> 1; off = 256 + (e & 1) * 128; }
  feats[b * 512 + off + c] = (a0 * w0 + a1 * w1) / (l0 * w0 + l1 * w1);
}

// ---------------------------------------------------------------------------
// Head
// ---------------------------------------------------------------------------
__global__ __launch_bounds__(128) void head_kernel(
    const float* __restrict__ feats, const float* __restrict__ hid_w,
    const float* __restrict__ hid_b, const float* __restrict__ out_w,
    const float* __restrict__ out_b, float* __restrict__ out) {
  __shared__ __align__(16) float f_s[512];
  __shared__ float part[2];
  int b = blockIdx.x, tid = threadIdx.x;
  for (int i = tid; i < 512; i += 128) f_s[i] = feats[b * 512 + i];
  __syncthreads();
  float h = hid_b[tid];
  for (int k = 0; k < 512; ++k) h += f_s[k] * hid_w[k * 128 + tid];
  h = fmaxf(h, 0.f);
  float p = h * out_w[tid];
#pragma unroll
  for (int off = 32; off > 0; off >>= 1) p += __shfl_xor(p, off, 64);
  if ((tid & 63) == 0) part[tid >> 6] = p;
  __syncthreads();
  if (tid == 0) out[b] = part[0] + part[1] + out_b[0];
}

// ---------------------------------------------------------------------------
extern "C" void kernel_launch(void* const* d_in, const int* in_sizes, int n_in,
                              void* d_out, int out_size, void* d_ws, size_t ws_size,
                              hipStream_t stream) {
  const int*   ctx     = (const int*)d_in[0];
  const int*   endseq  = (const int*)d_in[1];
  const int*   ctx_len = (const int*)d_in[2];
  const int*   end_len = (const int*)d_in[3];
  const float* emb     = (const float*)d_in[4];
  const float* fw_gw   = (const float*)d_in[5];
  const float* fw_gb   = (const float*)d_in[6];
  const float* fw_cw   = (const float*)d_in[7];
  const float* fw_cb   = (const float*)d_in[8];
  const float* bw_gw   = (const float*)d_in[9];
  const float* bw_gb   = (const float*)d_in[10];
  const float* bw_cw   = (const float*)d_in[11];
  const float* bw_cb   = (const float*)d_in[12];
  const float* att_v   = (const float*)d_in[13];
  const float* att_w   = (const float*)d_in[14];
  const float* att_b   = (const float*)d_in[15];
  const float* hid_w   = (const float*)d_in[16];
  const float* hid_b   = (const float*)d_in[17];
  const float* out_w   = (const float*)d_in[18];
  const float* out_b   = (const float*)d_in[19];
  float* ws  = (float*)d_ws;
  float* out = (float*)d_out;

  short* Ahi    = (short*)(ws + OFF_ST);
  short* Alo    = Ahi + (size_t)V_ * KP;
  short* Bthi   = (short*)(ws + OFF_BT);
  short* Btlo   = Bthi + (size_t)NCOL * KP;
  short* awt_hi = (short*)(ws + OFF_AWT);
  short* awt_lo = awt_hi + 128 * 128;
  float* partials = ws + OFF_BT;   // Bt region is dead after gemm

  pack_misc<<<1411, 256, 0, stream>>>(fw_gw, fw_gb, fw_cw, fw_cb,
                                      bw_gw, bw_gb, bw_cw, bw_cb, att_w,
                                      ws + OFF_UALL, ws + OFF_BIAS,
                                      Bthi, Btlo, awt_hi, awt_lo);
  pack_emb<<<(int)(((size_t)V_ * KP + 255) / 256), 256, 0, stream>>>(emb, Ahi, Alo);

  gemm_mfma<<<2346, 256, 0, stream>>>(Ahi, Alo, Bthi, Btlo, ws + OFF_PROJ);

  recur_kernel<<<512, 256, 0, stream>>>(ctx, endseq, ctx_len, end_len,
                                        ws + OFF_PROJ, ws + OFF_UALL,
                                        ws + OFF_BIAS, ws + OFF_ST);

  attn_kernel<<<768, 256, 0, stream>>>(ws + OFF_ST, awt_hi, awt_lo,
                                       att_v, att_b, partials);
  attn_merge_kernel<<<512, 128, 0, stream>>>(partials, ws + OFF_FEATS);

  head_kernel<<<128, 128, 0, stream>>>(ws + OFF_FEATS, hid_w, hid_b,
                                       out_w, out_b, out);
}